// Round 1
// baseline (180.427 us; speedup 1.0000x reference)
//
#include <hip/hip_runtime.h>
#include <math.h>

constexpr int B = 2, S = 2048, E = 1024, H = 16, D = 64;
constexpr int M = B * S;   // 4096
constexpr int NBIG = 3072; // fused q|k|v output width
constexpr int CH = 8;      // kv chunks per (b,h), 256 t each

typedef __attribute__((ext_vector_type(8))) _Float16 half8;
typedef __attribute__((ext_vector_type(4))) float f32x4;
#define MFMA_F16 __builtin_amdgcn_mfma_f32_16x16x32_f16
// wait until at most N vector-memory ops outstanding; leave lgkm/exp unconstrained
#define WAITCNT_VM(N) __builtin_amdgcn_s_waitcnt(0xF70 | (N))

__device__ __forceinline__ short f2h(float f) {
  _Float16 h = (_Float16)f;
  short s;
  __builtin_memcpy(&s, &h, 2);
  return s;
}
__device__ __forceinline__ float h2f(short s) {
  _Float16 h;
  __builtin_memcpy(&h, &s, 2);
  return (float)h;
}

// Async global->LDS DMA, 16B per lane. LDS dest = wave-uniform base + lane*16.
__device__ __forceinline__ void gload16(const void* g, const void* l) {
  __builtin_amdgcn_global_load_lds(
      (const __attribute__((address_space(1))) unsigned*)g,
      (__attribute__((address_space(3))) unsigned*)l, 16, 0, 0);
}

// Pipelined fp16 NT-GEMM core: acc[m][n] += A[bm+..][k]*B[bn+..][k] over K.
// BM in {64,128}, BN=128 fixed, 4 waves (2x2), swizzled LDS chunks, double buffer,
// raw s_barrier + s_waitcnt vmcnt(PW) mid-loop (prefetch stays in flight).
template <int BM>
__device__ __forceinline__ void gemm_core(const short* __restrict__ A,
                                          const short* __restrict__ Bm,
                                          int bm, int bn, int K, short* lds,
                                          f32x4 (&acc)[BM / 32][4]) {
  constexpr int SA = BM / 16, TOT = SA + 8, PW = TOT / 4, MT = BM / 32;
  const int tid = threadIdx.x, wave = tid >> 6, lane = tid & 63;

  const short* gb[PW];
#pragma unroll
  for (int j = 0; j < PW; ++j) {
    const int n = wave * PW + j;
    const short* src; int seg, rowbase;
    if (n < SA) { src = A;  seg = n;      rowbase = bm; }
    else        { src = Bm; seg = n - SA; rowbase = bn; }
    const int r = seg * 16 + (lane >> 2);   // row within tile
    const int p = lane & 3;                 // LDS chunk slot this lane fills
    const int q = (p - ((r >> 1) & 3)) & 3; // k-chunk that belongs in slot p (swizzle)
    gb[j] = src + (size_t)(rowbase + r) * K + q * 8;
  }
  const int fr = lane & 15, fq = lane >> 4;
  const int wm = (wave & 1) * (BM / 2), wn = (wave >> 1) * 64;
  int ao[MT], bo[4];
#pragma unroll
  for (int mi = 0; mi < MT; ++mi) {
    const int r = wm + mi * 16 + fr;
    ao[mi] = r * 32 + (((fq + ((r >> 1) & 3)) & 3)) * 8;
  }
#pragma unroll
  for (int ni = 0; ni < 4; ++ni) {
    const int r = wn + ni * 16 + fr;
    bo[ni] = BM * 32 + r * 32 + (((fq + ((r >> 1) & 3)) & 3)) * 8;
  }
  const int ldsW = wave * PW * 512;
  auto stageAll = [&](int buf, int k0) {
#pragma unroll
    for (int j = 0; j < PW; ++j)
      gload16(gb[j] + k0, &lds[buf * TOT * 512 + ldsW + j * 512]);
  };
  stageAll(0, 0);
  stageAll(1, 32);
  int buf = 0;
  for (int k0 = 0; k0 < K; k0 += 32) {
    if (k0 + 32 < K) WAITCNT_VM(PW); else WAITCNT_VM(0);
    __builtin_amdgcn_s_barrier();
    half8 ah[MT], bh4[4];
    const int bb = buf * TOT * 512;
#pragma unroll
    for (int mi = 0; mi < MT; ++mi) ah[mi] = *(const half8*)&lds[bb + ao[mi]];
#pragma unroll
    for (int ni = 0; ni < 4; ++ni) bh4[ni] = *(const half8*)&lds[bb + bo[ni]];
#pragma unroll
    for (int mi = 0; mi < MT; ++mi)
#pragma unroll
      for (int ni = 0; ni < 4; ++ni)
        acc[mi][ni] = MFMA_F16(ah[mi], bh4[ni], acc[mi][ni], 0, 0, 0);
    __builtin_amdgcn_s_barrier();  // all waves done reading lds[buf]
    if (k0 + 64 < K) stageAll(buf, k0 + 64);
    buf ^= 1;
  }
}

// prep_w (3329 blocks): weight fp16 conversions + transposes + bias combines +
// bv copy + Zk zero. (hs conversion moved into the wgemm dispatch.)
__global__ __launch_bounds__(256) void prep_w(
    const float* __restrict__ Wfq, short* Wfq_f,
    const float* __restrict__ Wfk, short* Wfk_f,
    const float* __restrict__ Wv, short* Wv_f,
    const float* __restrict__ Wq, short* WqT_f,
    const float* __restrict__ Wk, short* WkT_f,
    const float* __restrict__ bq, const float* __restrict__ bfq,
    const float* __restrict__ bk, const float* __restrict__ bfk,
    const float* __restrict__ bv, float* bcat, float* Zk) {
  __shared__ float tb[32][33];
  const int blk = blockIdx.x, tid = threadIdx.x;
  if (blk < 768) {
    const int base = blk;  // 256 each: Wfq, Wfk, Wv
    const float* src = (base < 256) ? Wfq : (base < 512 ? Wfk : Wv);
    short* dst = (base < 256) ? Wfq_f : (base < 512 ? Wfk_f : Wv_f);
    const int bb = base & 255;
#pragma unroll
    for (int p = 0; p < 4; ++p) {
      const int i = bb * 1024 + p * 256 + tid;  // float4 index
      float4 v = ((const float4*)src)[i];
      ((short4*)dst)[i] = make_short4(f2h(v.x), f2h(v.y), f2h(v.z), f2h(v.w));
    }
  } else if (blk < 2816) {
    const int t = blk - 768;
    const float* in = (t < 1024) ? Wq : Wk;
    short* oh = (t < 1024) ? WqT_f : WkT_f;
    const int tt = t & 1023;
    const int bx = (tt & 31) * 32, by = (tt >> 5) * 32;
    const int x = tid & 31, y0 = tid >> 5;
#pragma unroll
    for (int i = 0; i < 32; i += 8) tb[y0 + i][x] = in[(size_t)(by + y0 + i) * E + bx + x];
    __syncthreads();
#pragma unroll
    for (int i = 0; i < 32; i += 8)
      oh[(size_t)(bx + y0 + i) * E + by + x] = f2h(tb[x][y0 + i]);
  } else if (blk < 3328) {
    const int t = blk - 2816;
    const float* Wf = (t < 256) ? Wfq : Wfk;
    const float* bin = (t < 256) ? bq : bk;
    const float* bf = (t < 256) ? bfq : bfk;
    float* o = (t < 256) ? bcat : bcat + 1024;
    const int n = (t & 255) * 4 + (tid >> 6);
    const int lane = tid & 63;
    float sacc = 0.f;
    for (int j = lane; j < E; j += 64) sacc += Wf[(size_t)n * E + j] * bin[j];
#pragma unroll
    for (int off = 32; off; off >>= 1) sacc += __shfl_xor(sacc, off, 64);
    if (lane == 0) o[n] = sacc + bf[n];
  } else {
    // copy bv -> bcat[2048..3072) and zero Zk[4096]
    ((float4*)(bcat + 2048))[tid] = ((const float4*)bv)[tid];
#pragma unroll
    for (int p = 0; p < 4; ++p)
      ((float4*)Zk)[p * 256 + tid] = make_float4(0.f, 0.f, 0.f, 0.f);
  }
}

// Weight-combine GEMMs (z=0: WcQ = Wfq@Wq, z=1: WcK = Wfk@Wk) + hs fp16
// conversion as z=2 (fills the otherwise 256-block latency-bound dispatch).
__global__ __launch_bounds__(256, 3) void wgemm_hs(
    const short* __restrict__ Wfq_f, const short* __restrict__ WqT_f,
    const short* __restrict__ Wfk_f, const short* __restrict__ WkT_f,
    short* __restrict__ Wcat,
    const float* __restrict__ hs, short* __restrict__ hs_f) {
  __shared__ short lds[2 * 12 * 512];  // BM=64: TOT=12, 24 KB
  if (blockIdx.z == 2) {
    const int bid = blockIdx.y * 16 + blockIdx.x;  // 0..127
    const int stride = 128 * 256;
    for (int i = bid * 256 + threadIdx.x; i < M * E / 4; i += stride) {
      float4 v = ((const float4*)hs)[i];
      ((short4*)hs_f)[i] = make_short4(f2h(v.x), f2h(v.y), f2h(v.z), f2h(v.w));
    }
    return;
  }
  const short* A = blockIdx.z ? Wfk_f : Wfq_f;
  const short* Bm = blockIdx.z ? WkT_f : WqT_f;
  short* C = Wcat + (size_t)blockIdx.z * E * E;  // rows 0..1023 or 1024..2047
  const int bm = blockIdx.x * 64, bn = blockIdx.y * 128;
  f32x4 acc[2][4] = {};
  gemm_core<64>(A, Bm, bm, bn, E, lds, acc);
  const int lane = threadIdx.x & 63, wave = threadIdx.x >> 6;
  const int fr = lane & 15, fq = lane >> 4;
  const int wm = (wave & 1) * 32, wn = (wave >> 1) * 64;
#pragma unroll
  for (int ni = 0; ni < 4; ++ni) {
    const int n = bn + wn + ni * 16 + fr;
#pragma unroll
    for (int mi = 0; mi < 2; ++mi) {
      const int m0 = bm + wm + mi * 16 + fq * 4;
#pragma unroll
      for (int r2 = 0; r2 < 4; ++r2)
        C[(size_t)(m0 + r2) * E + n] = f2h(acc[mi][ni][r2]);
    }
  }
}

// Fused big GEMM: Cbig[M,3072] = hs_f @ [WcQ|WcK|Wv]^T + bcat, epilogue by range:
//   n<1024 (q): store exp(val);  1024..2047 (k): exp + Zk rowsum;  else (v): plain.
// Grid (24 n-blocks, 32 m-blocks) = 768 uniform blocks.
__global__ __launch_bounds__(256, 3) void gemm_big(
    const short* __restrict__ hs_f, const short* __restrict__ Wcat,
    const float* __restrict__ bcat, short* __restrict__ Cb,
    float* __restrict__ Zk) {
  __shared__ short lds[2 * 16 * 512];  // BM=128: TOT=16, 32 KB
  const int bm = blockIdx.y * 128, bn = blockIdx.x * 128;
  f32x4 acc[4][4] = {};
  gemm_core<128>(hs_f, Wcat, bm, bn, E, lds, acc);
  const int lane = threadIdx.x & 63, wave = threadIdx.x >> 6;
  const int fr = lane & 15, fq = lane >> 4;
  const int wm = (wave & 1) * 64, wn = (wave >> 1) * 64;
  const bool doExp = (bn < 2048);
  const bool doZ = (bn >= 1024) && (bn < 2048);
  float bv4[4];
#pragma unroll
  for (int ni = 0; ni < 4; ++ni) bv4[ni] = bcat[bn + wn + ni * 16 + fr];
#pragma unroll
  for (int mi = 0; mi < 4; ++mi)
#pragma unroll
    for (int r2 = 0; r2 < 4; ++r2) {
      const int m = bm + wm + mi * 16 + fq * 4 + r2;
      float vals[4];
#pragma unroll
      for (int ni = 0; ni < 4; ++ni) vals[ni] = acc[mi][ni][r2] + bv4[ni];
      if (doExp) {
#pragma unroll
        for (int ni = 0; ni < 4; ++ni) vals[ni] = __expf(vals[ni]);
      }
      if (doZ) {
        float es = vals[0] + vals[1] + vals[2] + vals[3];
#pragma unroll
        for (int off = 1; off < 16; off <<= 1) es += __shfl_xor(es, off, 16);
        if (fr == 0) atomicAdd(&Zk[m], es);
      }
#pragma unroll
      for (int ni = 0; ni < 4; ++ni)
        Cb[(size_t)m * NBIG + bn + wn + ni * 16 + fr] = f2h(vals[ni]);
    }
}

// Per-chunk KV partials. Grid (32 bh, CH=8 chunks of 256 t), 512 threads.
// R9: widened from 256 threads (1 wave/SIMD -> no latency hiding) to 512
// threads: waves 0-3 accumulate rows 0-15 of each 32-row stage, waves 4-7
// rows 16-31; one LDS reduction merges the halves. Per-thread serial FMA
// chain halves (4096 -> 2048) and 2 waves/SIMD hide LDS/global latency.
__global__ __launch_bounds__(512) void kv_part(const short* __restrict__ Cb,
                                               const float* __restrict__ Zk,
                                               float* __restrict__ KVp,
                                               float* __restrict__ ksump) {
  const int bh = blockIdx.x;
  const int b = bh / H, h = bh % H;
  const int t0 = blockIdx.y * 256;
  const short* kbase = Cb + (size_t)b * S * NBIG + 1024 + h * D;
  const short* vbase = Cb + (size_t)b * S * NBIG + 2048 + h * D;
  __shared__ float ks[32][D];
  __shared__ float vs[32][D];
  __shared__ float invZs[256];
  __shared__ float red[20][256];  // scalar layout: conflict-free b32 writes
  const int tid = threadIdx.x;
  if (tid < 256) invZs[tid] = 1.0f / Zk[b * S + t0 + tid];  // batch offset b*S!
  const int t2 = tid & 255;
  const int g = tid >> 8;                    // t-half group (wave-uniform)
  const int a4 = t2 & 15, b4 = t2 >> 4;
  const int lt = tid >> 4, d4 = (tid & 15) * 4;  // staging: 32 rows/stage
  float acc[4][4] = {};
  float ksm[4] = {};
  for (int ts = 0; ts < 256; ts += 32) {
    __syncthreads();
    const size_t roff = (size_t)(t0 + ts + lt) * NBIG + d4;
    short4 k4 = *(const short4*)(kbase + roff);
    short4 v4 = *(const short4*)(vbase + roff);
    const float iz = invZs[ts + lt];
    ks[lt][d4 + 0] = h2f(k4.x) * iz; ks[lt][d4 + 1] = h2f(k4.y) * iz;
    ks[lt][d4 + 2] = h2f(k4.z) * iz; ks[lt][d4 + 3] = h2f(k4.w) * iz;
    vs[lt][d4 + 0] = h2f(v4.x); vs[lt][d4 + 1] = h2f(v4.y);
    vs[lt][d4 + 2] = h2f(v4.z); vs[lt][d4 + 3] = h2f(v4.w);
    __syncthreads();
    const int tb = g * 16;
#pragma unroll
    for (int tt = 0; tt < 16; ++tt) {
      float kk4[4], vv4[4];
#pragma unroll
      for (int i = 0; i < 4; ++i) kk4[i] = ks[tb + tt][a4 * 4 + i];
#pragma unroll
      for (int j = 0; j < 4; ++j) vv4[j] = vs[tb + tt][b4 * 4 + j];
#pragma unroll
      for (int i = 0; i < 4; ++i) {
        ksm[i] += kk4[i];
#pragma unroll
        for (int j = 0; j < 4; ++j) acc[i][j] = fmaf(kk4[i], vv4[j], acc[i][j]);
      }
    }
  }
  __syncthreads();
  if (g) {
#pragma unroll
    for (int e = 0; e < 16; ++e) red[e][t2] = acc[e >> 2][e & 3];
#pragma unroll
    for (int i = 0; i < 4; ++i) red[16 + i][t2] = ksm[i];
  }
  __syncthreads();
  if (!g) {
#pragma unroll
    for (int i = 0; i < 4; ++i) {
      ksm[i] += red[16 + i][t2];
#pragma unroll
      for (int j = 0; j < 4; ++j) acc[i][j] += red[i * 4 + j][t2];
    }
    float* kvout = KVp + ((size_t)bh * CH + blockIdx.y) * 4096;
#pragma unroll
    for (int i = 0; i < 4; ++i)
      *(float4*)&kvout[(a4 * 4 + i) * 64 + b4 * 4] =
          make_float4(acc[i][0], acc[i][1], acc[i][2], acc[i][3]);
    if (b4 == 0)
      *(float4*)&ksump[((size_t)bh * CH + blockIdx.y) * 64 + a4 * 4] =
          make_float4(ksm[0], ksm[1], ksm[2], ksm[3]);
  }
}

// Output (fuses the partial reduction): grid (32 bh, 32 chunks of 64 rows).
// Reduces CH=8 KV partials into LDS (L2-resident reads), then per-row ratio.
__global__ __launch_bounds__(256) void out_v8(const short* __restrict__ Cb,
                                              const float* __restrict__ KVp,
                                              const float* __restrict__ ksump,
                                              float* __restrict__ out) {
  const int bh = blockIdx.x;
  const int b = bh >> 4, h = bh & 15;
  __shared__ float KVs[64][64];  // float4 reads are 2-way bank-aliased (free)
  __shared__ float kss[64];
  __shared__ float qs[4][4][64];
  const int tid = threadIdx.x, wave = tid >> 6, lane = tid & 63;
  const int r2 = lane >> 4, g = lane & 15;
  for (int i = tid; i < 1024; i += 256) {  // float4 index within 4096
    float4 s = make_float4(0.f, 0.f, 0.f, 0.f);
#pragma unroll
    for (int c = 0; c < CH; ++c) {
      float4 p = ((const float4*)(KVp + ((size_t)bh * CH + c) * 4096))[i];
      s.x += p.x; s.y += p.y; s.z += p.z; s.w += p.w;
    }
    ((float4*)KVs)[i] = s;
  }
  if (tid < 16) {
    float4 s = make_float4(0.f, 0.f, 0.f, 0.f);
#pragma unroll
    for (int c = 0; c < CH; ++c) {
      float4 p = ((const float4*)(ksump + ((size_t)bh * CH + c) * 64))[tid];
      s.x += p.x; s.y += p.y; s.z += p.z; s.w += p.w;
    }
    ((float4*)kss)[tid] = s;
  }
  __syncthreads();
  const float4 ks4 = *(const float4*)&kss[g * 4];
  const int row0 = blockIdx.y * 64 + wave * 16;
#pragma unroll
  for (int it = 0; it < 4; ++it) {
    const int row = row0 + it * 4 + r2;
    // u = stored exp(q logit) fp16 from Cbig (q range, stride 3072)
    short4 us = *(const short4*)(Cb + (size_t)(b * S + row) * NBIG + h * 64 + g * 4);
    float4 u = make_float4(h2f(us.x), h2f(us.y), h2f(us.z), h2f(us.w));
    float dn = u.x * ks4.x + u.y * ks4.y + u.z * ks4.z + u.w * ks4.w;
#pragma unroll
    for (int off = 1; off < 16; off <<= 1) dn += __shfl_xor(dn, off, 16);
    *(float4*)&qs[wave][r2][g * 4] = u;
    __syncthreads();  // publish qs (uniform: all waves run 4 iters)
    float nx = 0.f, ny = 0.f, nz = 0.f, nw = 0.f;
#pragma unroll
    for (int d = 0; d < 64; ++d) {
      const float qd = qs[wave][r2][d];
      const float4 kv = *(const float4*)&KVs[d][g * 4];
      nx = fmaf(qd, kv.x, nx); ny = fmaf(qd, kv.y, ny);
      nz = fmaf(qd, kv.z, nz); nw = fmaf(qd, kv.w, nw);
    }
    const float inv = 1.0f / dn;
    float4 o4 = make_float4(nx * inv, ny * inv, nz * inv, nw * inv);
    const size_t rowoff = ((size_t)b * S + row) * E + h * 64 + g * 4;
    *(float4*)(out + rowoff) = o4;
    __syncthreads();  // qs reused next iteration
  }
}

extern "C" void kernel_launch(void* const* d_in, const int* in_sizes, int n_in,
                              void* d_out, int out_size, void* d_ws, size_t ws_size,
                              hipStream_t stream) {
  const float* hs = (const float*)d_in[0];
  const float* Wq = (const float*)d_in[1];
  const float* bq = (const float*)d_in[2];
  const float* Wk = (const float*)d_in[3];
  const float* bk = (const float*)d_in[4];
  const float* Wv = (const float*)d_in[5];
  const float* bv = (const float*)d_in[6];
  const float* Wfq = (const float*)d_in[7];
  const float* bfq = (const float*)d_in[8];
  const float* Wfk = (const float*)d_in[9];
  const float* bfk = (const float*)d_in[10];
  float* out = (float*)d_out;

  const size_t MEG = 1024 * 1024;
  float* ws = (float*)d_ws;
  short* hs_f = (short*)ws;                            // [0,2M) floats (8 MB)
  short* Wfq_f = (short*)(ws + 2 * MEG);               // 0.5M floats each
  short* Wfk_f = (short*)(ws + 2 * MEG + MEG / 2);
  short* WqT_f = (short*)(ws + 3 * MEG);
  short* WkT_f = (short*)(ws + 3 * MEG + MEG / 2);
  short* Wcat = (short*)(ws + 4 * MEG);                // 3M shorts: [WcQ|WcK|Wv]
  short* Wv_f = Wcat + 2 * MEG;                        // rows 2048..3071
  float* bcat = ws + 6 * MEG;                          // 3072 floats
  float* Zk = bcat + 4096;                             // 4096 floats
  float* KVp = ws + 7 * MEG;                           // 32*CH*4096 = 1M floats
  float* ksump = ws + 8 * MEG;                         // 16K floats
  short* Cbig = (short*)(ws + 9 * MEG);                // M x 3072 fp16 (24 MB)

  // 1) Weight conversions + transposes + bias combines + bv copy + Zk zero.
  prep_w<<<3329, 256, 0, stream>>>(Wfq, Wfq_f, Wfk, Wfk_f, Wv, Wv_f,
                                   Wq, WqT_f, Wk, WkT_f,
                                   bq, bfq, bk, bfk, bv, bcat, Zk);
  // 2) Weight-combine GEMMs (z=0,1) + hs fp16 conversion (z=2), one dispatch.
  wgemm_hs<<<dim3(16, 8, 3), 256, 0, stream>>>(Wfq_f, WqT_f, Wfk_f, WkT_f,
                                               Wcat, hs, hs_f);
  // 3) Fused big GEMM: q|k|v in one N=3072 dispatch (768 uniform blocks).
  gemm_big<<<dim3(24, 32), 256, 0, stream>>>(hs_f, Wcat, bcat, Cbig, Zk);
  // 4) KV partials (256 blocks x 512 threads, t-split + LDS reduce).
  kv_part<<<dim3(B * H, CH), 512, 0, stream>>>(Cbig, Zk, KVp, ksump);
  // 5) Output (1024 blocks; fuses the CH-partial reduction).
  out_v8<<<dim3(B * H, S / 64), 256, 0, stream>>>(Cbig, KVp, ksump, out);
}

// Round 2
// 176.564 us; speedup vs baseline: 1.0219x; 1.0219x over previous
//
#include <hip/hip_runtime.h>
#include <math.h>

constexpr int B = 2, S = 2048, E = 1024, H = 16, D = 64;
constexpr int M = B * S;   // 4096
constexpr int NBIG = 3072; // fused q|k|v output width
constexpr int CH = 8;      // kv chunks per (b,h), 256 t each

typedef __attribute__((ext_vector_type(8))) _Float16 half8;
typedef __attribute__((ext_vector_type(8))) short short8;
typedef __attribute__((ext_vector_type(4))) float f32x4;
#define MFMA_F16 __builtin_amdgcn_mfma_f32_16x16x32_f16
// wait until at most N vector-memory ops outstanding; leave lgkm/exp unconstrained
#define WAITCNT_VM(N) __builtin_amdgcn_s_waitcnt(0xF70 | (N))

__device__ __forceinline__ short f2h(float f) {
  _Float16 h = (_Float16)f;
  short s;
  __builtin_memcpy(&s, &h, 2);
  return s;
}
__device__ __forceinline__ float h2f(short s) {
  _Float16 h;
  __builtin_memcpy(&h, &s, 2);
  return (float)h;
}

// Async global->LDS DMA, 16B per lane. LDS dest = wave-uniform base + lane*16.
__device__ __forceinline__ void gload16(const void* g, const void* l) {
  __builtin_amdgcn_global_load_lds(
      (const __attribute__((address_space(1))) unsigned*)g,
      (__attribute__((address_space(3))) unsigned*)l, 16, 0, 0);
}

// Pipelined fp16 NT-GEMM core: acc[m][n] += A[bm+..][k]*B[bn+..][k] over K.
// BM in {64,128}, BN=128 fixed, 4 waves (2x2), swizzled LDS chunks, double buffer,
// raw s_barrier + s_waitcnt vmcnt(PW) mid-loop (prefetch stays in flight).
template <int BM>
__device__ __forceinline__ void gemm_core(const short* __restrict__ A,
                                          const short* __restrict__ Bm,
                                          int bm, int bn, int K, short* lds,
                                          f32x4 (&acc)[BM / 32][4]) {
  constexpr int SA = BM / 16, TOT = SA + 8, PW = TOT / 4, MT = BM / 32;
  const int tid = threadIdx.x, wave = tid >> 6, lane = tid & 63;

  const short* gb[PW];
#pragma unroll
  for (int j = 0; j < PW; ++j) {
    const int n = wave * PW + j;
    const short* src; int seg, rowbase;
    if (n < SA) { src = A;  seg = n;      rowbase = bm; }
    else        { src = Bm; seg = n - SA; rowbase = bn; }
    const int r = seg * 16 + (lane >> 2);   // row within tile
    const int p = lane & 3;                 // LDS chunk slot this lane fills
    const int q = (p - ((r >> 1) & 3)) & 3; // k-chunk that belongs in slot p (swizzle)
    gb[j] = src + (size_t)(rowbase + r) * K + q * 8;
  }
  const int fr = lane & 15, fq = lane >> 4;
  const int wm = (wave & 1) * (BM / 2), wn = (wave >> 1) * 64;
  int ao[MT], bo[4];
#pragma unroll
  for (int mi = 0; mi < MT; ++mi) {
    const int r = wm + mi * 16 + fr;
    ao[mi] = r * 32 + (((fq + ((r >> 1) & 3)) & 3)) * 8;
  }
#pragma unroll
  for (int ni = 0; ni < 4; ++ni) {
    const int r = wn + ni * 16 + fr;
    bo[ni] = BM * 32 + r * 32 + (((fq + ((r >> 1) & 3)) & 3)) * 8;
  }
  const int ldsW = wave * PW * 512;
  auto stageAll = [&](int buf, int k0) {
#pragma unroll
    for (int j = 0; j < PW; ++j)
      gload16(gb[j] + k0, &lds[buf * TOT * 512 + ldsW + j * 512]);
  };
  stageAll(0, 0);
  stageAll(1, 32);
  int buf = 0;
  for (int k0 = 0; k0 < K; k0 += 32) {
    if (k0 + 32 < K) WAITCNT_VM(PW); else WAITCNT_VM(0);
    __builtin_amdgcn_s_barrier();
    half8 ah[MT], bh4[4];
    const int bb = buf * TOT * 512;
#pragma unroll
    for (int mi = 0; mi < MT; ++mi) ah[mi] = *(const half8*)&lds[bb + ao[mi]];
#pragma unroll
    for (int ni = 0; ni < 4; ++ni) bh4[ni] = *(const half8*)&lds[bb + bo[ni]];
#pragma unroll
    for (int mi = 0; mi < MT; ++mi)
#pragma unroll
      for (int ni = 0; ni < 4; ++ni)
        acc[mi][ni] = MFMA_F16(ah[mi], bh4[ni], acc[mi][ni], 0, 0, 0);
    __builtin_amdgcn_s_barrier();  // all waves done reading lds[buf]
    if (k0 + 64 < K) stageAll(buf, k0 + 64);
    buf ^= 1;
  }
}

// prep_w (3329 blocks): weight fp16 conversions + transposes + bias combines +
// bv copy + Zk zero. (hs conversion moved into the wgemm dispatch.)
__global__ __launch_bounds__(256) void prep_w(
    const float* __restrict__ Wfq, short* Wfq_f,
    const float* __restrict__ Wfk, short* Wfk_f,
    const float* __restrict__ Wv, short* Wv_f,
    const float* __restrict__ Wq, short* WqT_f,
    const float* __restrict__ Wk, short* WkT_f,
    const float* __restrict__ bq, const float* __restrict__ bfq,
    const float* __restrict__ bk, const float* __restrict__ bfk,
    const float* __restrict__ bv, float* bcat, float* Zk) {
  __shared__ float tb[32][33];
  const int blk = blockIdx.x, tid = threadIdx.x;
  if (blk < 768) {
    const int base = blk;  // 256 each: Wfq, Wfk, Wv
    const float* src = (base < 256) ? Wfq : (base < 512 ? Wfk : Wv);
    short* dst = (base < 256) ? Wfq_f : (base < 512 ? Wfk_f : Wv_f);
    const int bb = base & 255;
#pragma unroll
    for (int p = 0; p < 4; ++p) {
      const int i = bb * 1024 + p * 256 + tid;  // float4 index
      float4 v = ((const float4*)src)[i];
      ((short4*)dst)[i] = make_short4(f2h(v.x), f2h(v.y), f2h(v.z), f2h(v.w));
    }
  } else if (blk < 2816) {
    const int t = blk - 768;
    const float* in = (t < 1024) ? Wq : Wk;
    short* oh = (t < 1024) ? WqT_f : WkT_f;
    const int tt = t & 1023;
    const int bx = (tt & 31) * 32, by = (tt >> 5) * 32;
    const int x = tid & 31, y0 = tid >> 5;
#pragma unroll
    for (int i = 0; i < 32; i += 8) tb[y0 + i][x] = in[(size_t)(by + y0 + i) * E + bx + x];
    __syncthreads();
#pragma unroll
    for (int i = 0; i < 32; i += 8)
      oh[(size_t)(bx + y0 + i) * E + by + x] = f2h(tb[x][y0 + i]);
  } else if (blk < 3328) {
    const int t = blk - 2816;
    const float* Wf = (t < 256) ? Wfq : Wfk;
    const float* bin = (t < 256) ? bq : bk;
    const float* bf = (t < 256) ? bfq : bfk;
    float* o = (t < 256) ? bcat : bcat + 1024;
    const int n = (t & 255) * 4 + (tid >> 6);
    const int lane = tid & 63;
    float sacc = 0.f;
    for (int j = lane; j < E; j += 64) sacc += Wf[(size_t)n * E + j] * bin[j];
#pragma unroll
    for (int off = 32; off; off >>= 1) sacc += __shfl_xor(sacc, off, 64);
    if (lane == 0) o[n] = sacc + bf[n];
  } else {
    // copy bv -> bcat[2048..3072) and zero Zk[4096]
    ((float4*)(bcat + 2048))[tid] = ((const float4*)bv)[tid];
#pragma unroll
    for (int p = 0; p < 4; ++p)
      ((float4*)Zk)[p * 256 + tid] = make_float4(0.f, 0.f, 0.f, 0.f);
  }
}

// Weight-combine GEMMs (z=0: WcQ = Wfq@Wq, z=1: WcK = Wfk@Wk) + hs fp16
// conversion as z=2. R10: BM=64 -> BM=128 tiles (343 TF class -> ~900 TF
// class); grid (8,8,3): 128 GEMM blocks at 1/CU + 64 conv blocks concurrent.
__global__ __launch_bounds__(256, 3) void wgemm_hs(
    const short* __restrict__ Wfq_f, const short* __restrict__ WqT_f,
    const short* __restrict__ Wfk_f, const short* __restrict__ WkT_f,
    short* __restrict__ Wcat,
    const float* __restrict__ hs, short* __restrict__ hs_f) {
  __shared__ short lds[2 * 16 * 512];  // BM=128: TOT=16, 32 KB
  if (blockIdx.z == 2) {
    const int bid = blockIdx.y * 8 + blockIdx.x;  // 0..63
    const int stride = 64 * 256;
    for (int i = bid * 256 + threadIdx.x; i < M * E / 4; i += stride) {
      float4 v = ((const float4*)hs)[i];
      ((short4*)hs_f)[i] = make_short4(f2h(v.x), f2h(v.y), f2h(v.z), f2h(v.w));
    }
    return;
  }
  const short* A = blockIdx.z ? Wfk_f : Wfq_f;
  const short* Bm = blockIdx.z ? WkT_f : WqT_f;
  short* C = Wcat + (size_t)blockIdx.z * E * E;  // rows 0..1023 or 1024..2047
  const int bm = blockIdx.x * 128, bn = blockIdx.y * 128;
  f32x4 acc[4][4] = {};
  gemm_core<128>(A, Bm, bm, bn, E, lds, acc);
  const int lane = threadIdx.x & 63, wave = threadIdx.x >> 6;
  const int fr = lane & 15, fq = lane >> 4;
  const int wm = (wave & 1) * 64, wn = (wave >> 1) * 64;
#pragma unroll
  for (int ni = 0; ni < 4; ++ni) {
    const int n = bn + wn + ni * 16 + fr;
#pragma unroll
    for (int mi = 0; mi < 4; ++mi) {
      const int m0 = bm + wm + mi * 16 + fq * 4;
#pragma unroll
      for (int r2 = 0; r2 < 4; ++r2)
        C[(size_t)(m0 + r2) * E + n] = f2h(acc[mi][ni][r2]);
    }
  }
}

// Fused big GEMM: Cbig[M,3072] = hs_f @ [WcQ|WcK|Wv]^T + bcat, epilogue by range:
//   n<1024 (q): store exp(val);  1024..2047 (k): exp + Zk rowsum;  else (v): plain.
// Grid (24 n-blocks, 32 m-blocks) = 768 uniform blocks.
__global__ __launch_bounds__(256, 3) void gemm_big(
    const short* __restrict__ hs_f, const short* __restrict__ Wcat,
    const float* __restrict__ bcat, short* __restrict__ Cb,
    float* __restrict__ Zk) {
  __shared__ short lds[2 * 16 * 512];  // BM=128: TOT=16, 32 KB
  const int bm = blockIdx.y * 128, bn = blockIdx.x * 128;
  f32x4 acc[4][4] = {};
  gemm_core<128>(hs_f, Wcat, bm, bn, E, lds, acc);
  const int lane = threadIdx.x & 63, wave = threadIdx.x >> 6;
  const int fr = lane & 15, fq = lane >> 4;
  const int wm = (wave & 1) * 64, wn = (wave >> 1) * 64;
  const bool doExp = (bn < 2048);
  const bool doZ = (bn >= 1024) && (bn < 2048);
  float bv4[4];
#pragma unroll
  for (int ni = 0; ni < 4; ++ni) bv4[ni] = bcat[bn + wn + ni * 16 + fr];
#pragma unroll
  for (int mi = 0; mi < 4; ++mi)
#pragma unroll
    for (int r2 = 0; r2 < 4; ++r2) {
      const int m = bm + wm + mi * 16 + fq * 4 + r2;
      float vals[4];
#pragma unroll
      for (int ni = 0; ni < 4; ++ni) vals[ni] = acc[mi][ni][r2] + bv4[ni];
      if (doExp) {
#pragma unroll
        for (int ni = 0; ni < 4; ++ni) vals[ni] = __expf(vals[ni]);
      }
      if (doZ) {
        float es = vals[0] + vals[1] + vals[2] + vals[3];
#pragma unroll
        for (int off = 1; off < 16; off <<= 1) es += __shfl_xor(es, off, 16);
        if (fr == 0) atomicAdd(&Zk[m], es);
      }
#pragma unroll
      for (int ni = 0; ni < 4; ++ni)
        Cb[(size_t)m * NBIG + bn + wn + ni * 16 + fr] = f2h(vals[ni]);
    }
}

// Per-chunk KV partials. Grid (32 bh, CH=8 chunks of 256 t), 512 threads.
// Waves 0-3 accumulate rows 0-15 of each 32-row stage, waves 4-7 rows 16-31;
// one LDS reduction merges the halves. R10: float4 inner LDS reads
// (2x ds_read_b128 replaces 8x ds_read_b32 per tt).
__global__ __launch_bounds__(512) void kv_part(const short* __restrict__ Cb,
                                               const float* __restrict__ Zk,
                                               float* __restrict__ KVp,
                                               float* __restrict__ ksump) {
  const int bh = blockIdx.x;
  const int b = bh / H, h = bh % H;
  const int t0 = blockIdx.y * 256;
  const short* kbase = Cb + (size_t)b * S * NBIG + 1024 + h * D;
  const short* vbase = Cb + (size_t)b * S * NBIG + 2048 + h * D;
  __shared__ float ks[32][D];
  __shared__ float vs[32][D];
  __shared__ float invZs[256];
  __shared__ float red[20][256];  // scalar layout: conflict-free b32 writes
  const int tid = threadIdx.x;
  if (tid < 256) invZs[tid] = 1.0f / Zk[b * S + t0 + tid];  // batch offset b*S!
  const int t2 = tid & 255;
  const int g = tid >> 8;                    // t-half group (wave-uniform)
  const int a4 = t2 & 15, b4 = t2 >> 4;
  const int lt = tid >> 4, d4 = (tid & 15) * 4;  // staging: 32 rows/stage
  float acc[4][4] = {};
  float ksm[4] = {};
  for (int ts = 0; ts < 256; ts += 32) {
    __syncthreads();
    const size_t roff = (size_t)(t0 + ts + lt) * NBIG + d4;
    short4 k4 = *(const short4*)(kbase + roff);
    short4 v4 = *(const short4*)(vbase + roff);
    const float iz = invZs[ts + lt];
    ks[lt][d4 + 0] = h2f(k4.x) * iz; ks[lt][d4 + 1] = h2f(k4.y) * iz;
    ks[lt][d4 + 2] = h2f(k4.z) * iz; ks[lt][d4 + 3] = h2f(k4.w) * iz;
    vs[lt][d4 + 0] = h2f(v4.x); vs[lt][d4 + 1] = h2f(v4.y);
    vs[lt][d4 + 2] = h2f(v4.z); vs[lt][d4 + 3] = h2f(v4.w);
    __syncthreads();
    const int tb = g * 16;
#pragma unroll
    for (int tt = 0; tt < 16; ++tt) {
      const float4 kk = *(const float4*)&ks[tb + tt][a4 * 4];
      const float4 vv = *(const float4*)&vs[tb + tt][b4 * 4];
      const float kk4[4] = {kk.x, kk.y, kk.z, kk.w};
      const float vv4[4] = {vv.x, vv.y, vv.z, vv.w};
#pragma unroll
      for (int i = 0; i < 4; ++i) {
        ksm[i] += kk4[i];
#pragma unroll
        for (int j = 0; j < 4; ++j) acc[i][j] = fmaf(kk4[i], vv4[j], acc[i][j]);
      }
    }
  }
  __syncthreads();
  if (g) {
#pragma unroll
    for (int e = 0; e < 16; ++e) red[e][t2] = acc[e >> 2][e & 3];
#pragma unroll
    for (int i = 0; i < 4; ++i) red[16 + i][t2] = ksm[i];
  }
  __syncthreads();
  if (!g) {
#pragma unroll
    for (int i = 0; i < 4; ++i) {
      ksm[i] += red[16 + i][t2];
#pragma unroll
      for (int j = 0; j < 4; ++j) acc[i][j] += red[i * 4 + j][t2];
    }
    float* kvout = KVp + ((size_t)bh * CH + blockIdx.y) * 4096;
#pragma unroll
    for (int i = 0; i < 4; ++i)
      *(float4*)&kvout[(a4 * 4 + i) * 64 + b4 * 4] =
          make_float4(acc[i][0], acc[i][1], acc[i][2], acc[i][3]);
    if (b4 == 0)
      *(float4*)&ksump[((size_t)bh * CH + blockIdx.y) * 64 + a4 * 4] =
          make_float4(ksm[0], ksm[1], ksm[2], ksm[3]);
  }
}

// Output v9: grid (32 bh, 32 chunks of 64 rows). Reduces CH=8 KV partials
// into LDS, stages q TRANSPOSED (qs_t[wave][d][row]), then each thread
// register-blocks 4 rows x 4 cols: per d one KV float4 + one q float4 feed
// 16 FMAs (vs v8: 20 B LDS per 4 FMAs + 8 in-loop barriers -> 2 total).
__global__ __launch_bounds__(256) void out_v9(const short* __restrict__ Cb,
                                              const float* __restrict__ KVp,
                                              const float* __restrict__ ksump,
                                              float* __restrict__ out) {
  const int bh = blockIdx.x;
  const int b = bh >> 4, h = bh & 15;
  __shared__ float KVs[64][64];  // [d_k][d_v]; float4 reads 2-way aliased (free)
  __shared__ float kss[64];
  __shared__ float qs_t[4][64][20];  // per wave: [d][row 0..15], pad 20
  __shared__ float dns[64];
  const int tid = threadIdx.x, wave = tid >> 6, lane = tid & 63;
  const int g = lane & 15, rg = lane >> 4;
  const int row0 = blockIdx.y * 64;
  // q loads issued early: lane stages row (wave*16+g), d-chunk rg*16..+15
  const int qrow = row0 + wave * 16 + g;
  const int dstart = rg * 16;
  const short* qp = Cb + (size_t)(b * S + qrow) * NBIG + h * 64 + dstart;
  const short8 u8a = *(const short8*)qp;
  const short8 u8b = *(const short8*)(qp + 8);
  // KV partial reduce (global reads, L2-resident) + ksum reduce
  for (int i = tid; i < 1024; i += 256) {  // float4 index within 4096
    float4 s = make_float4(0.f, 0.f, 0.f, 0.f);
#pragma unroll
    for (int c = 0; c < CH; ++c) {
      float4 p = ((const float4*)(KVp + ((size_t)bh * CH + c) * 4096))[i];
      s.x += p.x; s.y += p.y; s.z += p.z; s.w += p.w;
    }
    ((float4*)KVs)[i] = s;
  }
  if (tid < 16) {
    float4 s = make_float4(0.f, 0.f, 0.f, 0.f);
#pragma unroll
    for (int c = 0; c < CH; ++c) {
      float4 p = ((const float4*)(ksump + ((size_t)bh * CH + c) * 64))[tid];
      s.x += p.x; s.y += p.y; s.z += p.z; s.w += p.w;
    }
    ((float4*)kss)[tid] = s;
  }
  __syncthreads();
  // stage q transposed + per-row denominator partial (needs kss)
  float uf[16];
#pragma unroll
  for (int j = 0; j < 8; ++j) { uf[j] = h2f(u8a[j]); uf[8 + j] = h2f(u8b[j]); }
  float dnp = 0.f;
#pragma unroll
  for (int j = 0; j < 16; ++j) {
    qs_t[wave][dstart + j][g] = uf[j];
    dnp = fmaf(uf[j], kss[dstart + j], dnp);
  }
  dnp += __shfl_xor(dnp, 16, 64);
  dnp += __shfl_xor(dnp, 32, 64);
  if (rg == 0) dns[wave * 16 + g] = dnp;
  __syncthreads();
  // main loop: thread owns rows (wave*16 + rg*4 .. +3) x cols (g*4 .. +3)
  float acc[4][4] = {};
#pragma unroll
  for (int d = 0; d < 64; ++d) {
    const float4 kv = *(const float4*)&KVs[d][g * 4];
    const float4 q4 = *(const float4*)&qs_t[wave][d][rg * 4];
    const float qa[4] = {q4.x, q4.y, q4.z, q4.w};
    const float ka[4] = {kv.x, kv.y, kv.z, kv.w};
#pragma unroll
    for (int i = 0; i < 4; ++i)
#pragma unroll
      for (int j = 0; j < 4; ++j) acc[i][j] = fmaf(qa[i], ka[j], acc[i][j]);
  }
#pragma unroll
  for (int i = 0; i < 4; ++i) {
    const int r = wave * 16 + rg * 4 + i;
    const float inv = 1.0f / dns[r];
    const int row = row0 + r;
    float4 o4 = make_float4(acc[i][0] * inv, acc[i][1] * inv,
                            acc[i][2] * inv, acc[i][3] * inv);
    *(float4*)(out + ((size_t)b * S + row) * E + h * 64 + g * 4) = o4;
  }
}

extern "C" void kernel_launch(void* const* d_in, const int* in_sizes, int n_in,
                              void* d_out, int out_size, void* d_ws, size_t ws_size,
                              hipStream_t stream) {
  const float* hs = (const float*)d_in[0];
  const float* Wq = (const float*)d_in[1];
  const float* bq = (const float*)d_in[2];
  const float* Wk = (const float*)d_in[3];
  const float* bk = (const float*)d_in[4];
  const float* Wv = (const float*)d_in[5];
  const float* bv = (const float*)d_in[6];
  const float* Wfq = (const float*)d_in[7];
  const float* bfq = (const float*)d_in[8];
  const float* Wfk = (const float*)d_in[9];
  const float* bfk = (const float*)d_in[10];
  float* out = (float*)d_out;

  const size_t MEG = 1024 * 1024;
  float* ws = (float*)d_ws;
  short* hs_f = (short*)ws;                            // [0,2M) floats (8 MB)
  short* Wfq_f = (short*)(ws + 2 * MEG);               // 0.5M floats each
  short* Wfk_f = (short*)(ws + 2 * MEG + MEG / 2);
  short* WqT_f = (short*)(ws + 3 * MEG);
  short* WkT_f = (short*)(ws + 3 * MEG + MEG / 2);
  short* Wcat = (short*)(ws + 4 * MEG);                // 3M shorts: [WcQ|WcK|Wv]
  short* Wv_f = Wcat + 2 * MEG;                        // rows 2048..3071
  float* bcat = ws + 6 * MEG;                          // 3072 floats
  float* Zk = bcat + 4096;                             // 4096 floats
  float* KVp = ws + 7 * MEG;                           // 32*CH*4096 = 1M floats
  float* ksump = ws + 8 * MEG;                         // 16K floats
  short* Cbig = (short*)(ws + 9 * MEG);                // M x 3072 fp16 (24 MB)

  // 1) Weight conversions + transposes + bias combines + bv copy + Zk zero.
  prep_w<<<3329, 256, 0, stream>>>(Wfq, Wfq_f, Wfk, Wfk_f, Wv, Wv_f,
                                   Wq, WqT_f, Wk, WkT_f,
                                   bq, bfq, bk, bfk, bv, bcat, Zk);
  // 2) Weight-combine GEMMs (z=0,1; BM=128) + hs fp16 conversion (z=2).
  wgemm_hs<<<dim3(8, 8, 3), 256, 0, stream>>>(Wfq_f, WqT_f, Wfk_f, WkT_f,
                                              Wcat, hs, hs_f);
  // 3) Fused big GEMM: q|k|v in one N=3072 dispatch (768 uniform blocks).
  gemm_big<<<dim3(24, 32), 256, 0, stream>>>(hs_f, Wcat, bcat, Cbig, Zk);
  // 4) KV partials (256 blocks x 512 threads, t-split + LDS reduce).
  kv_part<<<dim3(B * H, CH), 512, 0, stream>>>(Cbig, Zk, KVp, ksump);
  // 5) Output (1024 blocks; register-blocked 4x4 per thread).
  out_v9<<<dim3(B * H, S / 64), 256, 0, stream>>>(Cbig, KVp, ksump, out);
}